// Round 9
// baseline (270.772 us; speedup 1.0000x reference)
//
#include <hip/hip_runtime.h>
#include <math.h>

#define N_NODES 100000
#define N_EDGES 1200000
#define DIM 64
#define ELL_STRIDE 48        // ints per node row; deg<=48 safe (Poisson(12))
#define BNODES 128           // nodes per bucket (dst>>7)
#define NBUCKET ((N_NODES + BNODES - 1) / BNODES)   // 782 buckets
#define BIN_SHIFT 10         // coarse bin = dst>>10 (1024 nodes)
#define NBIN ((N_NODES + 1023) >> 10)               // 98 bins
#define BIN_CAP 16384        // edges per bin region; mean 12245, +37 sigma
#define CAP 40               // staged edges per bin per fill block; mean 23.9, +3.3 sigma
#define BIN_BLOCKS 512
#define EPB ((N_EDGES + BIN_BLOCKS - 1) / BIN_BLOCKS)  // 2344 edges/block
#define GEMM1_BLOCKS (N_NODES / 16)            // 6250 (16 nodes/block, exact)
#define GW_BLOCKS (N_NODES / 16)               // 6250 (16 nodes/block, exact)

// packed edge: bits 0-16 = src (<131072), bits 17-26 = dst & 1023
#define PACK(s, dloc) (((unsigned)(dloc) << 17) | (unsigned)(s))
#define UNPACK_S(p)   ((int)((p) & 0x1FFFF))
#define UNPACK_D(p)   ((int)((p) >> 17))

typedef __attribute__((ext_vector_type(8))) short bf16x8;
typedef __attribute__((ext_vector_type(4))) float f32x4;

// bf16 pack/unpack (RTNE)
__device__ __forceinline__ unsigned short f2bf(float f) {
    union { float f; unsigned int u; } v; v.f = f;
    unsigned int r = v.u + 0x7FFF + ((v.u >> 16) & 1);
    return (unsigned short)(r >> 16);
}
__device__ __forceinline__ float bf2f(unsigned short us) {
    return __uint_as_float((unsigned int)us << 16);
}

// gather load: ell stores BYTE offsets (src*128); addr = h + (off + 2*lane)
#define LDH(boff) bf2f(*(const unsigned short*)((const char*)h + ((unsigned)(boff) + bo)))

// split 8 fp32 (two float4) into bf16 hi + residual lo fragments
__device__ __forceinline__ void split8(const float4 p, const float4 q,
                                       bf16x8& hi, bf16x8& lo) {
    float v[8] = {p.x, p.y, p.z, p.w, q.x, q.y, q.z, q.w};
#pragma unroll
    for (int j = 0; j < 8; ++j) {               // compile-time index (rule #20 safe)
        unsigned short h0 = f2bf(v[j]);
        hi[j] = (short)h0;
        lo[j] = (short)f2bf(v[j] - bf2f(h0));
    }
}

// ---------------- gemm1 tile via MFMA: 16 nodes/block, no LDS ---------------
// Fragment conventions HW-validated rounds 7-8 (absmax unchanged).

__device__ __forceinline__ void gemm_block_mfma(int bid, const float* __restrict__ x,
                                                const float* __restrict__ W,
                                                unsigned short* __restrict__ h) {
    const int lane = (int)(threadIdx.x & 63);
    const int wv = (int)(threadIdx.x >> 6);
    const int base = bid * 16;
    const int g = lane >> 4;
    const int r16 = lane & 15;

    const float* xr = x + (size_t)(base + r16) * DIM + g * 8;
    float4 a0 = *(const float4*)(xr);
    float4 a1 = *(const float4*)(xr + 4);
    float4 a2 = *(const float4*)(xr + 32);
    float4 a3 = *(const float4*)(xr + 36);

    bf16x8 ah0, al0, ah1, al1;
    split8(a0, a1, ah0, al0);
    split8(a2, a3, ah1, al1);

    const int bcol = wv * 16 + r16;
    bf16x8 bh0, bl0, bh1, bl1;
#pragma unroll
    for (int j = 0; j < 8; ++j) {
        float w0 = W[(g * 8 + j) * DIM + bcol];
        float w1 = W[(g * 8 + j + 32) * DIM + bcol];
        unsigned short h0 = f2bf(w0);
        unsigned short h1 = f2bf(w1);
        bh0[j] = (short)h0; bl0[j] = (short)f2bf(w0 - bf2f(h0));
        bh1[j] = (short)h1; bl1[j] = (short)f2bf(w1 - bf2f(h1));
    }

    f32x4 acc = {0.f, 0.f, 0.f, 0.f};
    acc = __builtin_amdgcn_mfma_f32_16x16x32_bf16(ah0, bh0, acc, 0, 0, 0);
    acc = __builtin_amdgcn_mfma_f32_16x16x32_bf16(ah1, bh1, acc, 0, 0, 0);
    acc = __builtin_amdgcn_mfma_f32_16x16x32_bf16(al0, bh0, acc, 0, 0, 0);
    acc = __builtin_amdgcn_mfma_f32_16x16x32_bf16(al1, bh1, acc, 0, 0, 0);
    acc = __builtin_amdgcn_mfma_f32_16x16x32_bf16(ah0, bl0, acc, 0, 0, 0);
    acc = __builtin_amdgcn_mfma_f32_16x16x32_bf16(ah1, bl1, acc, 0, 0, 0);

#pragma unroll
    for (int r = 0; r < 4; ++r)
        h[(size_t)(base + g * 4 + r) * DIM + bcol] = f2bf(acc[r]);   // unscaled
}

// ---------------- fused: binning (blocks 0..511) || gemm1 (blocks 512..) ----
// Bin blocks FIRST: in-order dispatch starts the long-pole binning at t=0;
// the 6250 tiny gemm blocks fill remaining CUs concurrently (round-8 had
// them last -> phases serialized).

__global__ void __launch_bounds__(256, 8) k_pre(const int* __restrict__ ei,
                                                const float* __restrict__ x,
                                                const float* __restrict__ W1,
                                                int* __restrict__ tail,
                                                unsigned* __restrict__ part,
                                                unsigned short* __restrict__ h) {
    __shared__ unsigned stg[NBIN * CAP];          // 15.7 KB u32 staging
    __shared__ int lcnt[NBIN];
    __shared__ int gbase[NBIN];
    __shared__ int gcnt[NBIN];

    if (blockIdx.x >= BIN_BLOCKS) {
        gemm_block_mfma(blockIdx.x - BIN_BLOCKS, x, W1, h);
        return;
    }
    const int tid = threadIdx.x;
    for (int i = tid; i < NBIN; i += 256) lcnt[i] = 0;
    __syncthreads();

    const int e0 = blockIdx.x * EPB;
    const int eend = (e0 + EPB < N_EDGES) ? e0 + EPB : N_EDGES;
    for (int e = e0 + tid; e < eend; e += 256) {
        int s = ei[e], d = ei[N_EDGES + e];
        int bin = d >> BIN_SHIFT;
        unsigned pk = PACK(s, d & 1023);
        int pos = atomicAdd(&lcnt[bin], 1);
        if (pos < CAP) {
            stg[bin * CAP + pos] = pk;
        } else {                              // ~3.3-sigma tail, few hundred edges
            int gp = atomicAdd(&tail[bin * 16], 1);
            part[(size_t)bin * BIN_CAP + gp] = pk;
        }
    }
    __syncthreads();
    if (tid < NBIN) {
        int c = lcnt[tid]; if (c > CAP) c = CAP;
        gcnt[tid] = c;
        gbase[tid] = c ? atomicAdd(&tail[tid * 16], c) : 0;
    }
    __syncthreads();
    const int wv = tid >> 6, ln = tid & 63;   // wave-parallel flush (4 bins concurrent)
    for (int b = wv; b < NBIN; b += 4) {
        int c = gcnt[b];
        size_t gbb = (size_t)b * BIN_CAP + gbase[b];
        for (int i = ln; i < c; i += 64)
            part[gbb + i] = stg[b * CAP + i];
    }
}

// ---------------- bucket build: ELL slab in LDS + fused h1 scale ------------
// ELL entries are BYTE offsets into h (src * DIM * 2 = src << 7).

__global__ void __launch_bounds__(256) k_bucket(const unsigned* __restrict__ part,
                                                const int* __restrict__ tail,
                                                int* __restrict__ ell,
                                                int* __restrict__ deg,
                                                unsigned short* __restrict__ hA,
                                                unsigned short* __restrict__ hB) {
    __shared__ int lcur[BNODES];
    __shared__ int lell[BNODES * ELL_STRIDE];   // 24 KB
    const int bucket = blockIdx.x;
    const int tid = threadIdx.x;

    for (int i = tid; i < BNODES; i += 256) lcur[i] = 0;
    __syncthreads();

    const int bin = bucket >> 3;                // dst>>10 == (dst>>7)>>3
    const int sub = bucket & 7;
    const int n = tail[bin * 16];
    const unsigned* pb = part + (size_t)bin * BIN_CAP;
    const int node0 = bucket * BNODES;
    for (int i = tid; i < n; i += 256) {
        unsigned p = pb[i];
        unsigned ld = (unsigned)(UNPACK_D(p) - (sub << 7));
        if (ld < BNODES) {
            int pos = atomicAdd(&lcur[ld], 1);
            if (pos < ELL_STRIDE) lell[ld * ELL_STRIDE + pos] = UNPACK_S(p) << 7;
        }
    }
    __syncthreads();

    for (int idx = tid; idx < BNODES * ELL_STRIDE; idx += 256) {
        int ln = idx / ELL_STRIDE, sl = idx - ln * ELL_STRIDE;
        int dg = lcur[ln];
        int pe = (dg + 7) & ~7;
        if (pe < 16) pe = 16;
        if (sl >= dg && sl < pe) lell[idx] = N_NODES << 7;   // dummy zero row
    }
    __syncthreads();

    int4* dst4 = (int4*)(ell + (size_t)bucket * BNODES * ELL_STRIDE);
    const int4* src4 = (const int4*)lell;
    for (int i = tid; i < BNODES * ELL_STRIDE / 4; i += 256) dst4[i] = src4[i];
    for (int i = tid; i < BNODES; i += 256) deg[node0 + i] = lcur[i];

    // fused scale: hA[row] *= dinv; zero both dummy rows
    for (int i = tid; i < BNODES * 8; i += 256) {       // 8 uint4 per row
        int ln = i >> 3;
        int node = node0 + ln;
        if (node < N_NODES) {
            float dd = rsqrtf((float)(lcur[ln] + 1));
            uint4* p = (uint4*)(hA + (size_t)node * DIM) + (i & 7);
            uint4 v = *p;
            float lo, hi;
            lo = __uint_as_float(v.x << 16) * dd; hi = __uint_as_float(v.x & 0xFFFF0000u) * dd;
            v.x = (unsigned)f2bf(lo) | ((unsigned)f2bf(hi) << 16);
            lo = __uint_as_float(v.y << 16) * dd; hi = __uint_as_float(v.y & 0xFFFF0000u) * dd;
            v.y = (unsigned)f2bf(lo) | ((unsigned)f2bf(hi) << 16);
            lo = __uint_as_float(v.z << 16) * dd; hi = __uint_as_float(v.z & 0xFFFF0000u) * dd;
            v.z = (unsigned)f2bf(lo) | ((unsigned)f2bf(hi) << 16);
            lo = __uint_as_float(v.w << 16) * dd; hi = __uint_as_float(v.w & 0xFFFF0000u) * dd;
            v.w = (unsigned)f2bf(lo) | ((unsigned)f2bf(hi) << 16);
            *p = v;
        }
    }
    if (bucket == 0) {
        if (tid < 8)  ((uint4*)(hA + (size_t)N_NODES * DIM))[tid] = make_uint4(0, 0, 0, 0);
        else if (tid < 16) ((uint4*)(hB + (size_t)N_NODES * DIM))[tid - 8] = make_uint4(0, 0, 0, 0);
    }
}

// ---------------- fused gather+GEMM: agg -> +b -> relu -> @W(MFMA) -> *dinv -
// Round-7 body; launch_bounds 4 -> 6 waves/EU (occupancy cap 50% -> 75%;
// measured 49% at cap 50, latency-bound scaling was proportional in r5).

__global__ void __launch_bounds__(256, 6)
k_gatherW(const unsigned short* __restrict__ h,
          const int* __restrict__ deg,
          const int* __restrict__ ell,
          const float* __restrict__ bvec,
          const float* __restrict__ W,
          unsigned short* __restrict__ hout) {
    __shared__ unsigned short shb[2048];        // [0..1023] A-hi, [1024..2047] A-lo
    const int tid = threadIdx.x;
    const int lane = tid & 63;
    const int wv = tid >> 6;
    const int base = blockIdx.x * 16;           // 6250*16 = 100000 exact
    const float bl = bvec[lane];
    const unsigned bo = 2u * (unsigned)lane;

#pragma unroll 2
    for (int m = 0; m < 4; ++m) {
        int node = base + wv * 4 + m;
        int dg = __builtin_amdgcn_readfirstlane(deg[node]);
        const int* row = ell + (size_t)node * ELL_STRIDE;

        int4 e0 = ((const int4*)row)[0];
        int4 e1 = ((const int4*)row)[1];
        int4 e2 = ((const int4*)row)[2];
        int4 e3 = ((const int4*)row)[3];
        float own = LDH((unsigned)node * 128u);

        float v0  = LDH(e0.x);
        float v1  = LDH(e0.y);
        float v2  = LDH(e0.z);
        float v3  = LDH(e0.w);
        float v4  = LDH(e1.x);
        float v5  = LDH(e1.y);
        float v6  = LDH(e1.z);
        float v7  = LDH(e1.w);
        float v8  = LDH(e2.x);
        float v9  = LDH(e2.y);
        float v10 = LDH(e2.z);
        float v11 = LDH(e2.w);
        float v12 = LDH(e3.x);
        float v13 = LDH(e3.y);
        float v14 = LDH(e3.z);
        float v15 = LDH(e3.w);

        float acc = ((own + v0) + (v1 + v2)) + ((v3 + v4) + (v5 + v6))
                  + ((v7 + v8) + (v9 + v10)) + ((v11 + v12) + ((v13 + v14) + v15));

        if (dg > 16) {                          // rare, wave-uniform
            int pe = (dg + 7) & ~7;
            for (int k = 16; k < pe; k += 8) {
                int4 a = *(const int4*)(row + k);
                int4 c = *(const int4*)(row + k + 4);
                float w0 = LDH(a.x);
                float w1 = LDH(a.y);
                float w2 = LDH(a.z);
                float w3 = LDH(a.w);
                float w4 = LDH(c.x);
                float w5 = LDH(c.y);
                float w6 = LDH(c.z);
                float w7 = LDH(c.w);
                acc += ((w0 + w1) + (w2 + w3)) + ((w4 + w5) + (w6 + w7));
            }
        }

        float dd = rsqrtf((float)(dg + 1));
        float o = fmaxf(fmaf(acc, dd, bl), 0.f);    // bias + relu (layers 1,2)
        // split-bf16 store, chunk-swizzled: chunk = lane>>3, phys = chunk^(row&7)
        unsigned short oh = f2bf(o);
        unsigned short ol = f2bf(o - bf2f(oh));
        int r16 = wv * 4 + m;
        int pc = r16 * 64 + (((lane >> 3) ^ (r16 & 7)) << 3) + (lane & 7);
        shb[pc] = oh;
        shb[1024 + pc] = ol;
    }
    __syncthreads();

    // B fragments: wave wv covers output cols [wv*16, wv*16+16)
    const int bcol = wv * 16 + (lane & 15);
    const int g = lane >> 4;
    bf16x8 bh0, bl0, bh1, bl1;
#pragma unroll
    for (int j = 0; j < 8; ++j) {
        float w0 = W[(g * 8 + j) * DIM + bcol];
        float w1 = W[(g * 8 + j + 32) * DIM + bcol];
        unsigned short h0 = f2bf(w0);
        unsigned short h1 = f2bf(w1);
        bh0[j] = (short)h0; bl0[j] = (short)f2bf(w0 - bf2f(h0));
        bh1[j] = (short)h1; bl1[j] = (short)f2bf(w1 - bf2f(h1));
    }

    // A fragments: row = lane&15; undo chunk swizzle
    const int arow = lane & 15;
    const int cs = arow & 7;
    bf16x8 ah0 = *(const bf16x8*)&shb[arow * 64 + ((g ^ cs) << 3)];
    bf16x8 ah1 = *(const bf16x8*)&shb[arow * 64 + (((g + 4) ^ cs) << 3)];
    bf16x8 al0 = *(const bf16x8*)&shb[1024 + arow * 64 + ((g ^ cs) << 3)];
    bf16x8 al1 = *(const bf16x8*)&shb[1024 + arow * 64 + (((g + 4) ^ cs) << 3)];

    f32x4 acc = {0.f, 0.f, 0.f, 0.f};
    acc = __builtin_amdgcn_mfma_f32_16x16x32_bf16(ah0, bh0, acc, 0, 0, 0);
    acc = __builtin_amdgcn_mfma_f32_16x16x32_bf16(ah1, bh1, acc, 0, 0, 0);
    acc = __builtin_amdgcn_mfma_f32_16x16x32_bf16(al0, bh0, acc, 0, 0, 0);
    acc = __builtin_amdgcn_mfma_f32_16x16x32_bf16(al1, bh1, acc, 0, 0, 0);
    acc = __builtin_amdgcn_mfma_f32_16x16x32_bf16(ah0, bl0, acc, 0, 0, 0);
    acc = __builtin_amdgcn_mfma_f32_16x16x32_bf16(ah1, bl1, acc, 0, 0, 0);

#pragma unroll
    for (int r = 0; r < 4; ++r) {
        int rr = g * 4 + r;                     // C/D: row=(lane>>4)*4+r
        float res = acc[r] * rsqrtf((float)(deg[base + rr] + 1));
        hout[(size_t)(base + rr) * DIM + wv * 16 + (lane & 15)] = f2bf(res);
    }
}

// ---------------- final gather: out = dinv*(sum) + b (fp32) -----------------
// 1 node/wave, 25000 blocks; launch_bounds(256,8) -> up to 100% occupancy
// (body measured <=64 VGPR historically).

__global__ void __launch_bounds__(256, 8)
k_gatherF(const unsigned short* __restrict__ h,
          const int* __restrict__ deg,
          const int* __restrict__ ell, const float* __restrict__ b,
          float* __restrict__ out) {
    int node = blockIdx.x * 4 + (threadIdx.x >> 6);     // 25000*4 = 100000 exact
    const int lane = threadIdx.x & 63;
    const unsigned bo = 2u * (unsigned)lane;
    int dg = __builtin_amdgcn_readfirstlane(deg[node]);
    const int* row = ell + (size_t)node * ELL_STRIDE;

    int4 e0 = ((const int4*)row)[0];
    int4 e1 = ((const int4*)row)[1];
    int4 e2 = ((const int4*)row)[2];
    int4 e3 = ((const int4*)row)[3];
    float own = LDH((unsigned)node * 128u);

    float v0  = LDH(e0.x);
    float v1  = LDH(e0.y);
    float v2  = LDH(e0.z);
    float v3  = LDH(e0.w);
    float v4  = LDH(e1.x);
    float v5  = LDH(e1.y);
    float v6  = LDH(e1.z);
    float v7  = LDH(e1.w);
    float v8  = LDH(e2.x);
    float v9  = LDH(e2.y);
    float v10 = LDH(e2.z);
    float v11 = LDH(e2.w);
    float v12 = LDH(e3.x);
    float v13 = LDH(e3.y);
    float v14 = LDH(e3.z);
    float v15 = LDH(e3.w);

    float acc = ((own + v0) + (v1 + v2)) + ((v3 + v4) + (v5 + v6))
              + ((v7 + v8) + (v9 + v10)) + ((v11 + v12) + ((v13 + v14) + v15));

    if (dg > 16) {
        int pe = (dg + 7) & ~7;
        for (int k = 16; k < pe; k += 8) {
            int4 a = *(const int4*)(row + k);
            int4 c = *(const int4*)(row + k + 4);
            float w0 = LDH(a.x);
            float w1 = LDH(a.y);
            float w2 = LDH(a.z);
            float w3 = LDH(a.w);
            float w4 = LDH(c.x);
            float w5 = LDH(c.y);
            float w6 = LDH(c.z);
            float w7 = LDH(c.w);
            acc += ((w0 + w1) + (w2 + w3)) + ((w4 + w5) + (w6 + w7));
        }
    }

    float dd = rsqrtf((float)(dg + 1));
    out[(size_t)node * DIM + lane] = fmaf(acc, dd, b[lane]);
}

// ---------------- launch ----------------

extern "C" void kernel_launch(void* const* d_in, const int* in_sizes, int n_in,
                              void* d_out, int out_size, void* d_ws, size_t ws_size,
                              hipStream_t stream) {
    const float* x   = (const float*)d_in[0];
    const int*   ei  = (const int*)d_in[1];     // [2, E] row-major
    const float* W1  = (const float*)d_in[2];
    const float* b1  = (const float*)d_in[3];
    const float* W2  = (const float*)d_in[4];
    const float* b2  = (const float*)d_in[5];
    const float* W3  = (const float*)d_in[6];
    const float* b3  = (const float*)d_in[7];
    float* out = (float*)d_out;

    // ws layout; part (u32, 6.4 MB) overlays hbufB (disjoint lifetimes)
    char* ws = (char*)d_ws;
    int*            deg   = (int*)ws;                           // 400 KB
    int*            tailp = (int*)(ws + 0x70000);               // 98 x 64B
    int*            ell   = (int*)(ws + 0xD00000);              // 19.2 MB
    unsigned short* hbufA = (unsigned short*)(ws + 0x2000000);  // 12.8 MB (+dummy)
    unsigned short* hbufB = (unsigned short*)(ws + 0x2D00000);  // 12.85 MB
    unsigned*       part  = (unsigned*)(ws + 0x2D00000);        // overlay (NBIN*BIN_CAP*4)

    // zero the 98 bin tails (stream-ordered)
    hipMemsetAsync(tailp, 0, NBIN * 16 * sizeof(int), stream);

    // binning (blocks 0..511, long pole, starts first) || gemm1 MFMA
    k_pre<<<BIN_BLOCKS + GEMM1_BLOCKS, 256, 0, stream>>>(ei, x, W1, tailp, part, hbufA);
    // bucket ELL build (byte-offset entries) + deg + fused hbufA scale
    k_bucket<<<NBUCKET, 256, 0, stream>>>(part, tailp, ell, deg, hbufA, hbufB);

    // Layer 1->2: gather(h1') + b1 + relu -> @W2 *dinv -> hbufB
    k_gatherW<<<GW_BLOCKS, 256, 0, stream>>>(hbufA, deg, ell, b1, W2, hbufB);
    // Layer 2->3: -> @W3 *dinv -> hbufA
    k_gatherW<<<GW_BLOCKS, 256, 0, stream>>>(hbufB, deg, ell, b2, W3, hbufA);
    // Layer 3 final: fp32 out
    k_gatherF<<<N_NODES / 4, 256, 0, stream>>>(hbufA, deg, ell, b3, out);
}

// Round 10
// 242.379 us; speedup vs baseline: 1.1171x; 1.1171x over previous
//
#include <hip/hip_runtime.h>
#include <math.h>

#define N_NODES 100000
#define N_EDGES 1200000
#define DIM 64
#define ELL_STRIDE 48        // ints per node row; deg<=48 safe (Poisson(12))
#define BNODES 128           // nodes per bucket (dst>>7)
#define NBUCKET ((N_NODES + BNODES - 1) / BNODES)   // 782 buckets
#define BIN_SHIFT 10         // coarse bin = dst>>10 (1024 nodes)
#define NBIN ((N_NODES + 1023) >> 10)               // 98 bins
#define BIN_CAP 16384        // edges per bin region; mean 12245, +37 sigma
#define CAP 40               // staged edges per bin per fill block; mean 23.9, +3.3 sigma
#define BIN_BLOCKS 512
#define EPB ((N_EDGES + BIN_BLOCKS - 1) / BIN_BLOCKS)  // 2344 edges/block
#define GEMM1_BLOCKS (N_NODES / 16)            // 6250 (16 nodes/block, exact)
#define GW_BLOCKS (N_NODES / 16)               // 6250 (16 nodes/block, exact)

// packed edge: bits 0-16 = src (<131072), bits 17-26 = dst & 1023
#define PACK(s, dloc) (((unsigned)(dloc) << 17) | (unsigned)(s))
#define UNPACK_S(p)   ((int)((p) & 0x1FFFF))
#define UNPACK_D(p)   ((int)((p) >> 17))

typedef __attribute__((ext_vector_type(8))) short bf16x8;
typedef __attribute__((ext_vector_type(4))) float f32x4;

// bf16 pack/unpack (RTNE)
__device__ __forceinline__ unsigned short f2bf(float f) {
    union { float f; unsigned int u; } v; v.f = f;
    unsigned int r = v.u + 0x7FFF + ((v.u >> 16) & 1);
    return (unsigned short)(r >> 16);
}
__device__ __forceinline__ float bf2f(unsigned short us) {
    return __uint_as_float((unsigned int)us << 16);
}

// gather load: ell stores BYTE offsets (src*128); addr = h + (off + 2*lane)
#define LDH(boff) bf2f(*(const unsigned short*)((const char*)h + ((unsigned)(boff) + bo)))

// split 8 fp32 (two float4) into bf16 hi + residual lo fragments
__device__ __forceinline__ void split8(const float4 p, const float4 q,
                                       bf16x8& hi, bf16x8& lo) {
    float v[8] = {p.x, p.y, p.z, p.w, q.x, q.y, q.z, q.w};
#pragma unroll
    for (int j = 0; j < 8; ++j) {               // compile-time index (rule #20 safe)
        unsigned short h0 = f2bf(v[j]);
        hi[j] = (short)h0;
        lo[j] = (short)f2bf(v[j] - bf2f(h0));
    }
}

// ---------------- gemm1 tile via MFMA: 16 nodes/block, no LDS ---------------
// Fragment conventions HW-validated rounds 7-8 (absmax unchanged).
// NEEDS ~50-60 VGPRs: do NOT put occupancy launch_bounds on its kernel
// (round 9: __launch_bounds__(256,8) -> 32-VGPR cap -> spills -> +160 MB HBM).

__device__ __forceinline__ void gemm_block_mfma(int bid, const float* __restrict__ x,
                                                const float* __restrict__ W,
                                                unsigned short* __restrict__ h) {
    const int lane = (int)(threadIdx.x & 63);
    const int wv = (int)(threadIdx.x >> 6);
    const int base = bid * 16;
    const int g = lane >> 4;
    const int r16 = lane & 15;

    const float* xr = x + (size_t)(base + r16) * DIM + g * 8;
    float4 a0 = *(const float4*)(xr);
    float4 a1 = *(const float4*)(xr + 4);
    float4 a2 = *(const float4*)(xr + 32);
    float4 a3 = *(const float4*)(xr + 36);

    bf16x8 ah0, al0, ah1, al1;
    split8(a0, a1, ah0, al0);
    split8(a2, a3, ah1, al1);

    const int bcol = wv * 16 + r16;
    bf16x8 bh0, bl0, bh1, bl1;
#pragma unroll
    for (int j = 0; j < 8; ++j) {
        float w0 = W[(g * 8 + j) * DIM + bcol];
        float w1 = W[(g * 8 + j + 32) * DIM + bcol];
        unsigned short h0 = f2bf(w0);
        unsigned short h1 = f2bf(w1);
        bh0[j] = (short)h0; bl0[j] = (short)f2bf(w0 - bf2f(h0));
        bh1[j] = (short)h1; bl1[j] = (short)f2bf(w1 - bf2f(h1));
    }

    f32x4 acc = {0.f, 0.f, 0.f, 0.f};
    acc = __builtin_amdgcn_mfma_f32_16x16x32_bf16(ah0, bh0, acc, 0, 0, 0);
    acc = __builtin_amdgcn_mfma_f32_16x16x32_bf16(ah1, bh1, acc, 0, 0, 0);
    acc = __builtin_amdgcn_mfma_f32_16x16x32_bf16(al0, bh0, acc, 0, 0, 0);
    acc = __builtin_amdgcn_mfma_f32_16x16x32_bf16(al1, bh1, acc, 0, 0, 0);
    acc = __builtin_amdgcn_mfma_f32_16x16x32_bf16(ah0, bl0, acc, 0, 0, 0);
    acc = __builtin_amdgcn_mfma_f32_16x16x32_bf16(ah1, bl1, acc, 0, 0, 0);

#pragma unroll
    for (int r = 0; r < 4; ++r)
        h[(size_t)(base + g * 4 + r) * DIM + bcol] = f2bf(acc[r]);   // unscaled
}

// ---------------- fused: binning (blocks 0..511) || gemm1 (blocks 512..) ----
// Bin blocks FIRST: in-order dispatch starts the long-pole binning at t=0;
// the 6250 tiny gemm blocks fill remaining CUs concurrently.
// Default launch bounds: compiler picks VGPR (~44), no spills.

__global__ void __launch_bounds__(256) k_pre(const int* __restrict__ ei,
                                             const float* __restrict__ x,
                                             const float* __restrict__ W1,
                                             int* __restrict__ tail,
                                             unsigned* __restrict__ part,
                                             unsigned short* __restrict__ h) {
    __shared__ unsigned stg[NBIN * CAP];          // 15.7 KB u32 staging
    __shared__ int lcnt[NBIN];
    __shared__ int gbase[NBIN];
    __shared__ int gcnt[NBIN];

    if (blockIdx.x >= BIN_BLOCKS) {
        gemm_block_mfma(blockIdx.x - BIN_BLOCKS, x, W1, h);
        return;
    }
    const int tid = threadIdx.x;
    for (int i = tid; i < NBIN; i += 256) lcnt[i] = 0;
    __syncthreads();

    const int e0 = blockIdx.x * EPB;
    const int eend = (e0 + EPB < N_EDGES) ? e0 + EPB : N_EDGES;
    for (int e = e0 + tid; e < eend; e += 256) {
        int s = ei[e], d = ei[N_EDGES + e];
        int bin = d >> BIN_SHIFT;
        unsigned pk = PACK(s, d & 1023);
        int pos = atomicAdd(&lcnt[bin], 1);
        if (pos < CAP) {
            stg[bin * CAP + pos] = pk;
        } else {                              // ~3.3-sigma tail, few hundred edges
            int gp = atomicAdd(&tail[bin * 16], 1);
            part[(size_t)bin * BIN_CAP + gp] = pk;
        }
    }
    __syncthreads();
    if (tid < NBIN) {
        int c = lcnt[tid]; if (c > CAP) c = CAP;
        gcnt[tid] = c;
        gbase[tid] = c ? atomicAdd(&tail[tid * 16], c) : 0;
    }
    __syncthreads();
    const int wv = tid >> 6, ln = tid & 63;   // wave-parallel flush (4 bins concurrent)
    for (int b = wv; b < NBIN; b += 4) {
        int c = gcnt[b];
        size_t gbb = (size_t)b * BIN_CAP + gbase[b];
        for (int i = ln; i < c; i += 64)
            part[gbb + i] = stg[b * CAP + i];
    }
}

// ---------------- bucket build: ELL slab in LDS + fused h1 scale ------------
// ELL entries are BYTE offsets into h (src * DIM * 2 = src << 7).

__global__ void __launch_bounds__(256) k_bucket(const unsigned* __restrict__ part,
                                                const int* __restrict__ tail,
                                                int* __restrict__ ell,
                                                int* __restrict__ deg,
                                                unsigned short* __restrict__ hA,
                                                unsigned short* __restrict__ hB) {
    __shared__ int lcur[BNODES];
    __shared__ int lell[BNODES * ELL_STRIDE];   // 24 KB
    const int bucket = blockIdx.x;
    const int tid = threadIdx.x;

    for (int i = tid; i < BNODES; i += 256) lcur[i] = 0;
    __syncthreads();

    const int bin = bucket >> 3;                // dst>>10 == (dst>>7)>>3
    const int sub = bucket & 7;
    const int n = tail[bin * 16];
    const unsigned* pb = part + (size_t)bin * BIN_CAP;
    const int node0 = bucket * BNODES;
    for (int i = tid; i < n; i += 256) {
        unsigned p = pb[i];
        unsigned ld = (unsigned)(UNPACK_D(p) - (sub << 7));
        if (ld < BNODES) {
            int pos = atomicAdd(&lcur[ld], 1);
            if (pos < ELL_STRIDE) lell[ld * ELL_STRIDE + pos] = UNPACK_S(p) << 7;
        }
    }
    __syncthreads();

    for (int idx = tid; idx < BNODES * ELL_STRIDE; idx += 256) {
        int ln = idx / ELL_STRIDE, sl = idx - ln * ELL_STRIDE;
        int dg = lcur[ln];
        int pe = (dg + 7) & ~7;
        if (pe < 16) pe = 16;
        if (sl >= dg && sl < pe) lell[idx] = N_NODES << 7;   // dummy zero row
    }
    __syncthreads();

    int4* dst4 = (int4*)(ell + (size_t)bucket * BNODES * ELL_STRIDE);
    const int4* src4 = (const int4*)lell;
    for (int i = tid; i < BNODES * ELL_STRIDE / 4; i += 256) dst4[i] = src4[i];
    for (int i = tid; i < BNODES; i += 256) deg[node0 + i] = lcur[i];

    // fused scale: hA[row] *= dinv; zero both dummy rows
    for (int i = tid; i < BNODES * 8; i += 256) {       // 8 uint4 per row
        int ln = i >> 3;
        int node = node0 + ln;
        if (node < N_NODES) {
            float dd = rsqrtf((float)(lcur[ln] + 1));
            uint4* p = (uint4*)(hA + (size_t)node * DIM) + (i & 7);
            uint4 v = *p;
            float lo, hi;
            lo = __uint_as_float(v.x << 16) * dd; hi = __uint_as_float(v.x & 0xFFFF0000u) * dd;
            v.x = (unsigned)f2bf(lo) | ((unsigned)f2bf(hi) << 16);
            lo = __uint_as_float(v.y << 16) * dd; hi = __uint_as_float(v.y & 0xFFFF0000u) * dd;
            v.y = (unsigned)f2bf(lo) | ((unsigned)f2bf(hi) << 16);
            lo = __uint_as_float(v.z << 16) * dd; hi = __uint_as_float(v.z & 0xFFFF0000u) * dd;
            v.z = (unsigned)f2bf(lo) | ((unsigned)f2bf(hi) << 16);
            lo = __uint_as_float(v.w << 16) * dd; hi = __uint_as_float(v.w & 0xFFFF0000u) * dd;
            v.w = (unsigned)f2bf(lo) | ((unsigned)f2bf(hi) << 16);
            *p = v;
        }
    }
    if (bucket == 0) {
        if (tid < 8)  ((uint4*)(hA + (size_t)N_NODES * DIM))[tid] = make_uint4(0, 0, 0, 0);
        else if (tid < 16) ((uint4*)(hB + (size_t)N_NODES * DIM))[tid - 8] = make_uint4(0, 0, 0, 0);
    }
}

// ---------------- fused gather+GEMM: agg -> +b -> relu -> @W(MFMA) -> *dinv -
// Round-7 body; (256,6) measured neutral/no-spill in round 9 — kept.

__global__ void __launch_bounds__(256, 6)
k_gatherW(const unsigned short* __restrict__ h,
          const int* __restrict__ deg,
          const int* __restrict__ ell,
          const float* __restrict__ bvec,
          const float* __restrict__ W,
          unsigned short* __restrict__ hout) {
    __shared__ unsigned short shb[2048];        // [0..1023] A-hi, [1024..2047] A-lo
    const int tid = threadIdx.x;
    const int lane = tid & 63;
    const int wv = tid >> 6;
    const int base = blockIdx.x * 16;           // 6250*16 = 100000 exact
    const float bl = bvec[lane];
    const unsigned bo = 2u * (unsigned)lane;

#pragma unroll 2
    for (int m = 0; m < 4; ++m) {
        int node = base + wv * 4 + m;
        int dg = __builtin_amdgcn_readfirstlane(deg[node]);
        const int* row = ell + (size_t)node * ELL_STRIDE;

        int4 e0 = ((const int4*)row)[0];
        int4 e1 = ((const int4*)row)[1];
        int4 e2 = ((const int4*)row)[2];
        int4 e3 = ((const int4*)row)[3];
        float own = LDH((unsigned)node * 128u);

        float v0  = LDH(e0.x);
        float v1  = LDH(e0.y);
        float v2  = LDH(e0.z);
        float v3  = LDH(e0.w);
        float v4  = LDH(e1.x);
        float v5  = LDH(e1.y);
        float v6  = LDH(e1.z);
        float v7  = LDH(e1.w);
        float v8  = LDH(e2.x);
        float v9  = LDH(e2.y);
        float v10 = LDH(e2.z);
        float v11 = LDH(e2.w);
        float v12 = LDH(e3.x);
        float v13 = LDH(e3.y);
        float v14 = LDH(e3.z);
        float v15 = LDH(e3.w);

        float acc = ((own + v0) + (v1 + v2)) + ((v3 + v4) + (v5 + v6))
                  + ((v7 + v8) + (v9 + v10)) + ((v11 + v12) + ((v13 + v14) + v15));

        if (dg > 16) {                          // rare, wave-uniform
            int pe = (dg + 7) & ~7;
            for (int k = 16; k < pe; k += 8) {
                int4 a = *(const int4*)(row + k);
                int4 c = *(const int4*)(row + k + 4);
                float w0 = LDH(a.x);
                float w1 = LDH(a.y);
                float w2 = LDH(a.z);
                float w3 = LDH(a.w);
                float w4 = LDH(c.x);
                float w5 = LDH(c.y);
                float w6 = LDH(c.z);
                float w7 = LDH(c.w);
                acc += ((w0 + w1) + (w2 + w3)) + ((w4 + w5) + (w6 + w7));
            }
        }

        float dd = rsqrtf((float)(dg + 1));
        float o = fmaxf(fmaf(acc, dd, bl), 0.f);    // bias + relu (layers 1,2)
        // split-bf16 store, chunk-swizzled: chunk = lane>>3, phys = chunk^(row&7)
        unsigned short oh = f2bf(o);
        unsigned short ol = f2bf(o - bf2f(oh));
        int r16 = wv * 4 + m;
        int pc = r16 * 64 + (((lane >> 3) ^ (r16 & 7)) << 3) + (lane & 7);
        shb[pc] = oh;
        shb[1024 + pc] = ol;
    }
    __syncthreads();

    // B fragments: wave wv covers output cols [wv*16, wv*16+16)
    const int bcol = wv * 16 + (lane & 15);
    const int g = lane >> 4;
    bf16x8 bh0, bl0, bh1, bl1;
#pragma unroll
    for (int j = 0; j < 8; ++j) {
        float w0 = W[(g * 8 + j) * DIM + bcol];
        float w1 = W[(g * 8 + j + 32) * DIM + bcol];
        unsigned short h0 = f2bf(w0);
        unsigned short h1 = f2bf(w1);
        bh0[j] = (short)h0; bl0[j] = (short)f2bf(w0 - bf2f(h0));
        bh1[j] = (short)h1; bl1[j] = (short)f2bf(w1 - bf2f(h1));
    }

    // A fragments: row = lane&15; undo chunk swizzle
    const int arow = lane & 15;
    const int cs = arow & 7;
    bf16x8 ah0 = *(const bf16x8*)&shb[arow * 64 + ((g ^ cs) << 3)];
    bf16x8 ah1 = *(const bf16x8*)&shb[arow * 64 + (((g + 4) ^ cs) << 3)];
    bf16x8 al0 = *(const bf16x8*)&shb[1024 + arow * 64 + ((g ^ cs) << 3)];
    bf16x8 al1 = *(const bf16x8*)&shb[1024 + arow * 64 + (((g + 4) ^ cs) << 3)];

    f32x4 acc = {0.f, 0.f, 0.f, 0.f};
    acc = __builtin_amdgcn_mfma_f32_16x16x32_bf16(ah0, bh0, acc, 0, 0, 0);
    acc = __builtin_amdgcn_mfma_f32_16x16x32_bf16(ah1, bh1, acc, 0, 0, 0);
    acc = __builtin_amdgcn_mfma_f32_16x16x32_bf16(al0, bh0, acc, 0, 0, 0);
    acc = __builtin_amdgcn_mfma_f32_16x16x32_bf16(al1, bh1, acc, 0, 0, 0);
    acc = __builtin_amdgcn_mfma_f32_16x16x32_bf16(ah0, bl0, acc, 0, 0, 0);
    acc = __builtin_amdgcn_mfma_f32_16x16x32_bf16(ah1, bl1, acc, 0, 0, 0);

#pragma unroll
    for (int r = 0; r < 4; ++r) {
        int rr = g * 4 + r;                     // C/D: row=(lane>>4)*4+r
        float res = acc[r] * rsqrtf((float)(deg[base + rr] + 1));
        hout[(size_t)(base + rr) * DIM + wv * 16 + (lane & 15)] = f2bf(res);
    }
}

// ---------------- final gather: out = dinv*(sum) + b (fp32) -----------------
// 1 node/wave, 25000 blocks; (256,8) measured no-spill (body ~40 VGPR).

__global__ void __launch_bounds__(256, 8)
k_gatherF(const unsigned short* __restrict__ h,
          const int* __restrict__ deg,
          const int* __restrict__ ell, const float* __restrict__ b,
          float* __restrict__ out) {
    int node = blockIdx.x * 4 + (threadIdx.x >> 6);     // 25000*4 = 100000 exact
    const int lane = threadIdx.x & 63;
    const unsigned bo = 2u * (unsigned)lane;
    int dg = __builtin_amdgcn_readfirstlane(deg[node]);
    const int* row = ell + (size_t)node * ELL_STRIDE;

    int4 e0 = ((const int4*)row)[0];
    int4 e1 = ((const int4*)row)[1];
    int4 e2 = ((const int4*)row)[2];
    int4 e3 = ((const int4*)row)[3];
    float own = LDH((unsigned)node * 128u);

    float v0  = LDH(e0.x);
    float v1  = LDH(e0.y);
    float v2  = LDH(e0.z);
    float v3  = LDH(e0.w);
    float v4  = LDH(e1.x);
    float v5  = LDH(e1.y);
    float v6  = LDH(e1.z);
    float v7  = LDH(e1.w);
    float v8  = LDH(e2.x);
    float v9  = LDH(e2.y);
    float v10 = LDH(e2.z);
    float v11 = LDH(e2.w);
    float v12 = LDH(e3.x);
    float v13 = LDH(e3.y);
    float v14 = LDH(e3.z);
    float v15 = LDH(e3.w);

    float acc = ((own + v0) + (v1 + v2)) + ((v3 + v4) + (v5 + v6))
              + ((v7 + v8) + (v9 + v10)) + ((v11 + v12) + ((v13 + v14) + v15));

    if (dg > 16) {
        int pe = (dg + 7) & ~7;
        for (int k = 16; k < pe; k += 8) {
            int4 a = *(const int4*)(row + k);
            int4 c = *(const int4*)(row + k + 4);
            float w0 = LDH(a.x);
            float w1 = LDH(a.y);
            float w2 = LDH(a.z);
            float w3 = LDH(a.w);
            float w4 = LDH(c.x);
            float w5 = LDH(c.y);
            float w6 = LDH(c.z);
            float w7 = LDH(c.w);
            acc += ((w0 + w1) + (w2 + w3)) + ((w4 + w5) + (w6 + w7));
        }
    }

    float dd = rsqrtf((float)(dg + 1));
    out[(size_t)node * DIM + lane] = fmaf(acc, dd, b[lane]);
}

// ---------------- launch ----------------

extern "C" void kernel_launch(void* const* d_in, const int* in_sizes, int n_in,
                              void* d_out, int out_size, void* d_ws, size_t ws_size,
                              hipStream_t stream) {
    const float* x   = (const float*)d_in[0];
    const int*   ei  = (const int*)d_in[1];     // [2, E] row-major
    const float* W1  = (const float*)d_in[2];
    const float* b1  = (const float*)d_in[3];
    const float* W2  = (const float*)d_in[4];
    const float* b2  = (const float*)d_in[5];
    const float* W3  = (const float*)d_in[6];
    const float* b3  = (const float*)d_in[7];
    float* out = (float*)d_out;

    // ws layout; part (u32, 6.4 MB) overlays hbufB (disjoint lifetimes)
    char* ws = (char*)d_ws;
    int*            deg   = (int*)ws;                           // 400 KB
    int*            tailp = (int*)(ws + 0x70000);               // 98 x 64B
    int*            ell   = (int*)(ws + 0xD00000);              // 19.2 MB
    unsigned short* hbufA = (unsigned short*)(ws + 0x2000000);  // 12.8 MB (+dummy)
    unsigned short* hbufB = (unsigned short*)(ws + 0x2D00000);  // 12.85 MB
    unsigned*       part  = (unsigned*)(ws + 0x2D00000);        // overlay (NBIN*BIN_CAP*4)

    // zero the 98 bin tails (stream-ordered)
    hipMemsetAsync(tailp, 0, NBIN * 16 * sizeof(int), stream);

    // binning (blocks 0..511, long pole, starts first) || gemm1 MFMA
    k_pre<<<BIN_BLOCKS + GEMM1_BLOCKS, 256, 0, stream>>>(ei, x, W1, tailp, part, hbufA);
    // bucket ELL build (byte-offset entries) + deg + fused hbufA scale
    k_bucket<<<NBUCKET, 256, 0, stream>>>(part, tailp, ell, deg, hbufA, hbufB);

    // Layer 1->2: gather(h1') + b1 + relu -> @W2 *dinv -> hbufB
    k_gatherW<<<GW_BLOCKS, 256, 0, stream>>>(hbufA, deg, ell, b1, W2, hbufB);
    // Layer 2->3: -> @W3 *dinv -> hbufA
    k_gatherW<<<GW_BLOCKS, 256, 0, stream>>>(hbufB, deg, ell, b2, W3, hbufA);
    // Layer 3 final: fp32 out
    k_gatherF<<<N_NODES / 4, 256, 0, stream>>>(hbufA, deg, ell, b3, out);
}

// Round 11
// 238.288 us; speedup vs baseline: 1.1363x; 1.0172x over previous
//
#include <hip/hip_runtime.h>
#include <math.h>

#define N_NODES 100000
#define N_EDGES 1200000
#define DIM 64
#define ELL_STRIDE 48        // ints per node row; deg<=48 safe (Poisson(12))
#define BNODES 128           // nodes per bucket (dst>>7)
#define NBUCKET ((N_NODES + BNODES - 1) / BNODES)   // 782 buckets
#define BIN_SHIFT 10         // coarse bin = dst>>10 (1024 nodes)
#define NBIN ((N_NODES + 1023) >> 10)               // 98 bins
#define BIN_CAP 16384        // edges per bin region (8 shards x 2048)
#define NSHARD 8             // tail shards per bin (chain depth 512 -> 64)
#define SHARD_CAP (BIN_CAP / NSHARD)                // 2048; mean 1531, +13 sigma
#define CAP 40               // staged edges per bin per fill block; mean 23.9, +3.3 sigma
#define BIN_BLOCKS 512
#define EPB ((N_EDGES + BIN_BLOCKS - 1) / BIN_BLOCKS)  // 2344 edges/block
#define GEMM1_BLOCKS (N_NODES / 16)            // 6250 (16 nodes/block, exact)
#define GW_BLOCKS (N_NODES / 16)               // 6250 (16 nodes/block, exact)

// packed edge: bits 0-16 = src (<131072), bits 17-26 = dst & 1023
#define PACK(s, dloc) (((unsigned)(dloc) << 17) | (unsigned)(s))
#define UNPACK_S(p)   ((int)((p) & 0x1FFFF))
#define UNPACK_D(p)   ((int)((p) >> 17))

typedef __attribute__((ext_vector_type(8))) short bf16x8;
typedef __attribute__((ext_vector_type(4))) float f32x4;

// bf16 pack/unpack (RTNE)
__device__ __forceinline__ unsigned short f2bf(float f) {
    union { float f; unsigned int u; } v; v.f = f;
    unsigned int r = v.u + 0x7FFF + ((v.u >> 16) & 1);
    return (unsigned short)(r >> 16);
}
__device__ __forceinline__ float bf2f(unsigned short us) {
    return __uint_as_float((unsigned int)us << 16);
}

// gather load: ell stores BYTE offsets (src*128); addr = h + (off + 2*lane)
#define LDH(boff) bf2f(*(const unsigned short*)((const char*)h + ((unsigned)(boff) + bo)))

// split 8 fp32 (two float4) into bf16 hi + residual lo fragments
__device__ __forceinline__ void split8(const float4 p, const float4 q,
                                       bf16x8& hi, bf16x8& lo) {
    float v[8] = {p.x, p.y, p.z, p.w, q.x, q.y, q.z, q.w};
#pragma unroll
    for (int j = 0; j < 8; ++j) {               // compile-time index (rule #20 safe)
        unsigned short h0 = f2bf(v[j]);
        hi[j] = (short)h0;
        lo[j] = (short)f2bf(v[j] - bf2f(h0));
    }
}

// ---------------- gemm1 tile via MFMA: 16 nodes/block, no LDS ---------------
// Fragment conventions HW-validated rounds 7-10 (absmax unchanged).
// NEEDS ~50-60 VGPRs: do NOT put occupancy launch_bounds on its kernel
// (round 9: (256,8) -> 32-VGPR cap -> spills -> +160 MB HBM).

__device__ __forceinline__ void gemm_block_mfma(int bid, const float* __restrict__ x,
                                                const float* __restrict__ W,
                                                unsigned short* __restrict__ h) {
    const int lane = (int)(threadIdx.x & 63);
    const int wv = (int)(threadIdx.x >> 6);
    const int base = bid * 16;
    const int g = lane >> 4;
    const int r16 = lane & 15;

    const float* xr = x + (size_t)(base + r16) * DIM + g * 8;
    float4 a0 = *(const float4*)(xr);
    float4 a1 = *(const float4*)(xr + 4);
    float4 a2 = *(const float4*)(xr + 32);
    float4 a3 = *(const float4*)(xr + 36);

    bf16x8 ah0, al0, ah1, al1;
    split8(a0, a1, ah0, al0);
    split8(a2, a3, ah1, al1);

    const int bcol = wv * 16 + r16;
    bf16x8 bh0, bl0, bh1, bl1;
#pragma unroll
    for (int j = 0; j < 8; ++j) {
        float w0 = W[(g * 8 + j) * DIM + bcol];
        float w1 = W[(g * 8 + j + 32) * DIM + bcol];
        unsigned short h0 = f2bf(w0);
        unsigned short h1 = f2bf(w1);
        bh0[j] = (short)h0; bl0[j] = (short)f2bf(w0 - bf2f(h0));
        bh1[j] = (short)h1; bl1[j] = (short)f2bf(w1 - bf2f(h1));
    }

    f32x4 acc = {0.f, 0.f, 0.f, 0.f};
    acc = __builtin_amdgcn_mfma_f32_16x16x32_bf16(ah0, bh0, acc, 0, 0, 0);
    acc = __builtin_amdgcn_mfma_f32_16x16x32_bf16(ah1, bh1, acc, 0, 0, 0);
    acc = __builtin_amdgcn_mfma_f32_16x16x32_bf16(al0, bh0, acc, 0, 0, 0);
    acc = __builtin_amdgcn_mfma_f32_16x16x32_bf16(al1, bh1, acc, 0, 0, 0);
    acc = __builtin_amdgcn_mfma_f32_16x16x32_bf16(ah0, bl0, acc, 0, 0, 0);
    acc = __builtin_amdgcn_mfma_f32_16x16x32_bf16(ah1, bl1, acc, 0, 0, 0);

#pragma unroll
    for (int r = 0; r < 4; ++r)
        h[(size_t)(base + g * 4 + r) * DIM + bcol] = f2bf(acc[r]);   // unscaled
}

// ---------------- fused: binning (blocks 0..511) || gemm1 (blocks 512..) ----
// Bin blocks FIRST (long pole starts at t=0; gemm blocks backfill).
// Bin tails sharded 8x: tail line (bin*8+shard)*16, shard = blockIdx&7 —
// same-line atomic chain depth 512 -> 64, 98 contended lines -> 784.

__global__ void __launch_bounds__(256) k_pre(const int* __restrict__ ei,
                                             const float* __restrict__ x,
                                             const float* __restrict__ W1,
                                             int* __restrict__ tail,
                                             unsigned* __restrict__ part,
                                             unsigned short* __restrict__ h) {
    __shared__ unsigned stg[NBIN * CAP];          // 15.7 KB u32 staging
    __shared__ int lcnt[NBIN];
    __shared__ int gbase[NBIN];
    __shared__ int gcnt[NBIN];

    if (blockIdx.x >= BIN_BLOCKS) {
        gemm_block_mfma(blockIdx.x - BIN_BLOCKS, x, W1, h);
        return;
    }
    const int tid = threadIdx.x;
    const int shard = blockIdx.x & (NSHARD - 1);
    for (int i = tid; i < NBIN; i += 256) lcnt[i] = 0;
    __syncthreads();

    const int e0 = blockIdx.x * EPB;
    const int eend = (e0 + EPB < N_EDGES) ? e0 + EPB : N_EDGES;
    for (int e = e0 + tid; e < eend; e += 256) {
        int s = ei[e], d = ei[N_EDGES + e];
        int bin = d >> BIN_SHIFT;
        unsigned pk = PACK(s, d & 1023);
        int pos = atomicAdd(&lcnt[bin], 1);
        if (pos < CAP) {
            stg[bin * CAP + pos] = pk;
        } else {                              // ~3.3-sigma tail, few hundred edges
            int gp = atomicAdd(&tail[(bin * NSHARD + shard) * 16], 1);
            part[(size_t)bin * BIN_CAP + shard * SHARD_CAP + gp] = pk;
        }
    }
    __syncthreads();
    if (tid < NBIN) {
        int c = lcnt[tid]; if (c > CAP) c = CAP;
        gcnt[tid] = c;
        gbase[tid] = c ? atomicAdd(&tail[(tid * NSHARD + shard) * 16], c) : 0;
    }
    __syncthreads();
    const int wv = tid >> 6, ln = tid & 63;   // wave-parallel flush (4 bins concurrent)
    for (int b = wv; b < NBIN; b += 4) {
        int c = gcnt[b];
        size_t gbb = (size_t)b * BIN_CAP + shard * SHARD_CAP + gbase[b];
        for (int i = ln; i < c; i += 64)
            part[gbb + i] = stg[b * CAP + i];
    }
}

// ---------------- bucket build: ELL slab in LDS + fused h1 scale ------------
// ELL entries are BYTE offsets into h (src * DIM * 2 = src << 7).
// Drains the 8 shard sub-segments of its parent bin.

__global__ void __launch_bounds__(256) k_bucket(const unsigned* __restrict__ part,
                                                const int* __restrict__ tail,
                                                int* __restrict__ ell,
                                                int* __restrict__ deg,
                                                unsigned short* __restrict__ hA,
                                                unsigned short* __restrict__ hB) {
    __shared__ int lcur[BNODES];
    __shared__ int lell[BNODES * ELL_STRIDE];   // 24 KB
    const int bucket = blockIdx.x;
    const int tid = threadIdx.x;

    for (int i = tid; i < BNODES; i += 256) lcur[i] = 0;
    __syncthreads();

    const int bin = bucket >> 3;                // dst>>10 == (dst>>7)>>3
    const int sub = bucket & 7;
    const int node0 = bucket * BNODES;
    const unsigned* pb = part + (size_t)bin * BIN_CAP;
#pragma unroll 1
    for (int s = 0; s < NSHARD; ++s) {          // independent appends; no barrier
        int n = tail[(bin * NSHARD + s) * 16];
        const unsigned* ps = pb + s * SHARD_CAP;
        for (int i = tid; i < n; i += 256) {
            unsigned p = ps[i];
            unsigned ld = (unsigned)(UNPACK_D(p) - (sub << 7));
            if (ld < BNODES) {
                int pos = atomicAdd(&lcur[ld], 1);
                if (pos < ELL_STRIDE) lell[ld * ELL_STRIDE + pos] = UNPACK_S(p) << 7;
            }
        }
    }
    __syncthreads();

    for (int idx = tid; idx < BNODES * ELL_STRIDE; idx += 256) {
        int ln = idx / ELL_STRIDE, sl = idx - ln * ELL_STRIDE;
        int dg = lcur[ln];
        int pe = (dg + 7) & ~7;
        if (pe < 16) pe = 16;
        if (sl >= dg && sl < pe) lell[idx] = N_NODES << 7;   // dummy zero row
    }
    __syncthreads();

    int4* dst4 = (int4*)(ell + (size_t)bucket * BNODES * ELL_STRIDE);
    const int4* src4 = (const int4*)lell;
    for (int i = tid; i < BNODES * ELL_STRIDE / 4; i += 256) dst4[i] = src4[i];
    for (int i = tid; i < BNODES; i += 256) deg[node0 + i] = lcur[i];

    // fused scale: hA[row] *= dinv; zero both dummy rows
    for (int i = tid; i < BNODES * 8; i += 256) {       // 8 uint4 per row
        int ln = i >> 3;
        int node = node0 + ln;
        if (node < N_NODES) {
            float dd = rsqrtf((float)(lcur[ln] + 1));
            uint4* p = (uint4*)(hA + (size_t)node * DIM) + (i & 7);
            uint4 v = *p;
            float lo, hi;
            lo = __uint_as_float(v.x << 16) * dd; hi = __uint_as_float(v.x & 0xFFFF0000u) * dd;
            v.x = (unsigned)f2bf(lo) | ((unsigned)f2bf(hi) << 16);
            lo = __uint_as_float(v.y << 16) * dd; hi = __uint_as_float(v.y & 0xFFFF0000u) * dd;
            v.y = (unsigned)f2bf(lo) | ((unsigned)f2bf(hi) << 16);
            lo = __uint_as_float(v.z << 16) * dd; hi = __uint_as_float(v.z & 0xFFFF0000u) * dd;
            v.z = (unsigned)f2bf(lo) | ((unsigned)f2bf(hi) << 16);
            lo = __uint_as_float(v.w << 16) * dd; hi = __uint_as_float(v.w & 0xFFFF0000u) * dd;
            v.w = (unsigned)f2bf(lo) | ((unsigned)f2bf(hi) << 16);
            *p = v;
        }
    }
    if (bucket == 0) {
        if (tid < 8)  ((uint4*)(hA + (size_t)N_NODES * DIM))[tid] = make_uint4(0, 0, 0, 0);
        else if (tid < 16) ((uint4*)(hB + (size_t)N_NODES * DIM))[tid - 8] = make_uint4(0, 0, 0, 0);
    }
}

// ---------------- fused gather+GEMM: agg -> +b -> relu -> @W(MFMA) -> *dinv -
// Round-7 body; (256,6), no spills (round 9/10).

__global__ void __launch_bounds__(256, 6)
k_gatherW(const unsigned short* __restrict__ h,
          const int* __restrict__ deg,
          const int* __restrict__ ell,
          const float* __restrict__ bvec,
          const float* __restrict__ W,
          unsigned short* __restrict__ hout) {
    __shared__ unsigned short shb[2048];        // [0..1023] A-hi, [1024..2047] A-lo
    const int tid = threadIdx.x;
    const int lane = tid & 63;
    const int wv = tid >> 6;
    const int base = blockIdx.x * 16;           // 6250*16 = 100000 exact
    const float bl = bvec[lane];
    const unsigned bo = 2u * (unsigned)lane;

#pragma unroll 2
    for (int m = 0; m < 4; ++m) {
        int node = base + wv * 4 + m;
        int dg = __builtin_amdgcn_readfirstlane(deg[node]);
        const int* row = ell + (size_t)node * ELL_STRIDE;

        int4 e0 = ((const int4*)row)[0];
        int4 e1 = ((const int4*)row)[1];
        int4 e2 = ((const int4*)row)[2];
        int4 e3 = ((const int4*)row)[3];
        float own = LDH((unsigned)node * 128u);

        float v0  = LDH(e0.x);
        float v1  = LDH(e0.y);
        float v2  = LDH(e0.z);
        float v3  = LDH(e0.w);
        float v4  = LDH(e1.x);
        float v5  = LDH(e1.y);
        float v6  = LDH(e1.z);
        float v7  = LDH(e1.w);
        float v8  = LDH(e2.x);
        float v9  = LDH(e2.y);
        float v10 = LDH(e2.z);
        float v11 = LDH(e2.w);
        float v12 = LDH(e3.x);
        float v13 = LDH(e3.y);
        float v14 = LDH(e3.z);
        float v15 = LDH(e3.w);

        float acc = ((own + v0) + (v1 + v2)) + ((v3 + v4) + (v5 + v6))
                  + ((v7 + v8) + (v9 + v10)) + ((v11 + v12) + ((v13 + v14) + v15));

        if (dg > 16) {                          // rare, wave-uniform
            int pe = (dg + 7) & ~7;
            for (int k = 16; k < pe; k += 8) {
                int4 a = *(const int4*)(row + k);
                int4 c = *(const int4*)(row + k + 4);
                float w0 = LDH(a.x);
                float w1 = LDH(a.y);
                float w2 = LDH(a.z);
                float w3 = LDH(a.w);
                float w4 = LDH(c.x);
                float w5 = LDH(c.y);
                float w6 = LDH(c.z);
                float w7 = LDH(c.w);
                acc += ((w0 + w1) + (w2 + w3)) + ((w4 + w5) + (w6 + w7));
            }
        }

        float dd = rsqrtf((float)(dg + 1));
        float o = fmaxf(fmaf(acc, dd, bl), 0.f);    // bias + relu (layers 1,2)
        // split-bf16 store, chunk-swizzled: chunk = lane>>3, phys = chunk^(row&7)
        unsigned short oh = f2bf(o);
        unsigned short ol = f2bf(o - bf2f(oh));
        int r16 = wv * 4 + m;
        int pc = r16 * 64 + (((lane >> 3) ^ (r16 & 7)) << 3) + (lane & 7);
        shb[pc] = oh;
        shb[1024 + pc] = ol;
    }
    __syncthreads();

    // B fragments: wave wv covers output cols [wv*16, wv*16+16)
    const int bcol = wv * 16 + (lane & 15);
    const int g = lane >> 4;
    bf16x8 bh0, bl0, bh1, bl1;
#pragma unroll
    for (int j = 0; j < 8; ++j) {
        float w0 = W[(g * 8 + j) * DIM + bcol];
        float w1 = W[(g * 8 + j + 32) * DIM + bcol];
        unsigned short h0 = f2bf(w0);
        unsigned short h1 = f2bf(w1);
        bh0[j] = (short)h0; bl0[j] = (short)f2bf(w0 - bf2f(h0));
        bh1[j] = (short)h1; bl1[j] = (short)f2bf(w1 - bf2f(h1));
    }

    // A fragments: row = lane&15; undo chunk swizzle
    const int arow = lane & 15;
    const int cs = arow & 7;
    bf16x8 ah0 = *(const bf16x8*)&shb[arow * 64 + ((g ^ cs) << 3)];
    bf16x8 ah1 = *(const bf16x8*)&shb[arow * 64 + (((g + 4) ^ cs) << 3)];
    bf16x8 al0 = *(const bf16x8*)&shb[1024 + arow * 64 + ((g ^ cs) << 3)];
    bf16x8 al1 = *(const bf16x8*)&shb[1024 + arow * 64 + (((g + 4) ^ cs) << 3)];

    f32x4 acc = {0.f, 0.f, 0.f, 0.f};
    acc = __builtin_amdgcn_mfma_f32_16x16x32_bf16(ah0, bh0, acc, 0, 0, 0);
    acc = __builtin_amdgcn_mfma_f32_16x16x32_bf16(ah1, bh1, acc, 0, 0, 0);
    acc = __builtin_amdgcn_mfma_f32_16x16x32_bf16(al0, bh0, acc, 0, 0, 0);
    acc = __builtin_amdgcn_mfma_f32_16x16x32_bf16(al1, bh1, acc, 0, 0, 0);
    acc = __builtin_amdgcn_mfma_f32_16x16x32_bf16(ah0, bl0, acc, 0, 0, 0);
    acc = __builtin_amdgcn_mfma_f32_16x16x32_bf16(ah1, bl1, acc, 0, 0, 0);

#pragma unroll
    for (int r = 0; r < 4; ++r) {
        int rr = g * 4 + r;                     // C/D: row=(lane>>4)*4+r
        float res = acc[r] * rsqrtf((float)(deg[base + rr] + 1));
        hout[(size_t)(base + rr) * DIM + wv * 16 + (lane & 15)] = f2bf(res);
    }
}

// ---------------- final gather: out = dinv*(sum) + b (fp32) -----------------
// 1 node/wave, 25000 blocks; (256,8), no spills (body ~40 VGPR).

__global__ void __launch_bounds__(256, 8)
k_gatherF(const unsigned short* __restrict__ h,
          const int* __restrict__ deg,
          const int* __restrict__ ell, const float* __restrict__ b,
          float* __restrict__ out) {
    int node = blockIdx.x * 4 + (threadIdx.x >> 6);     // 25000*4 = 100000 exact
    const int lane = threadIdx.x & 63;
    const unsigned bo = 2u * (unsigned)lane;
    int dg = __builtin_amdgcn_readfirstlane(deg[node]);
    const int* row = ell + (size_t)node * ELL_STRIDE;

    int4 e0 = ((const int4*)row)[0];
    int4 e1 = ((const int4*)row)[1];
    int4 e2 = ((const int4*)row)[2];
    int4 e3 = ((const int4*)row)[3];
    float own = LDH((unsigned)node * 128u);

    float v0  = LDH(e0.x);
    float v1  = LDH(e0.y);
    float v2  = LDH(e0.z);
    float v3  = LDH(e0.w);
    float v4  = LDH(e1.x);
    float v5  = LDH(e1.y);
    float v6  = LDH(e1.z);
    float v7  = LDH(e1.w);
    float v8  = LDH(e2.x);
    float v9  = LDH(e2.y);
    float v10 = LDH(e2.z);
    float v11 = LDH(e2.w);
    float v12 = LDH(e3.x);
    float v13 = LDH(e3.y);
    float v14 = LDH(e3.z);
    float v15 = LDH(e3.w);

    float acc = ((own + v0) + (v1 + v2)) + ((v3 + v4) + (v5 + v6))
              + ((v7 + v8) + (v9 + v10)) + ((v11 + v12) + ((v13 + v14) + v15));

    if (dg > 16) {
        int pe = (dg + 7) & ~7;
        for (int k = 16; k < pe; k += 8) {
            int4 a = *(const int4*)(row + k);
            int4 c = *(const int4*)(row + k + 4);
            float w0 = LDH(a.x);
            float w1 = LDH(a.y);
            float w2 = LDH(a.z);
            float w3 = LDH(a.w);
            float w4 = LDH(c.x);
            float w5 = LDH(c.y);
            float w6 = LDH(c.z);
            float w7 = LDH(c.w);
            acc += ((w0 + w1) + (w2 + w3)) + ((w4 + w5) + (w6 + w7));
        }
    }

    float dd = rsqrtf((float)(dg + 1));
    out[(size_t)node * DIM + lane] = fmaf(acc, dd, b[lane]);
}

// ---------------- launch ----------------

extern "C" void kernel_launch(void* const* d_in, const int* in_sizes, int n_in,
                              void* d_out, int out_size, void* d_ws, size_t ws_size,
                              hipStream_t stream) {
    const float* x   = (const float*)d_in[0];
    const int*   ei  = (const int*)d_in[1];     // [2, E] row-major
    const float* W1  = (const float*)d_in[2];
    const float* b1  = (const float*)d_in[3];
    const float* W2  = (const float*)d_in[4];
    const float* b2  = (const float*)d_in[5];
    const float* W3  = (const float*)d_in[6];
    const float* b3  = (const float*)d_in[7];
    float* out = (float*)d_out;

    // ws layout; part (u32, 6.4 MB) overlays hbufB (disjoint lifetimes)
    char* ws = (char*)d_ws;
    int*            deg   = (int*)ws;                           // 400 KB
    int*            tailp = (int*)(ws + 0x70000);               // 98*8 x 64B = 50 KB
    int*            ell   = (int*)(ws + 0xD00000);              // 19.2 MB
    unsigned short* hbufA = (unsigned short*)(ws + 0x2000000);  // 12.8 MB (+dummy)
    unsigned short* hbufB = (unsigned short*)(ws + 0x2D00000);  // 12.85 MB
    unsigned*       part  = (unsigned*)(ws + 0x2D00000);        // overlay (NBIN*BIN_CAP*4)

    // zero the 98*8 sharded bin tails (stream-ordered)
    hipMemsetAsync(tailp, 0, NBIN * NSHARD * 16 * sizeof(int), stream);

    // binning (blocks 0..511, long pole, starts first) || gemm1 MFMA
    k_pre<<<BIN_BLOCKS + GEMM1_BLOCKS, 256, 0, stream>>>(ei, x, W1, tailp, part, hbufA);
    // bucket ELL build (byte-offset entries, 8 shard segments) + deg + scale
    k_bucket<<<NBUCKET, 256, 0, stream>>>(part, tailp, ell, deg, hbufA, hbufB);

    // Layer 1->2: gather(h1') + b1 + relu -> @W2 *dinv -> hbufB
    k_gatherW<<<GW_BLOCKS, 256, 0, stream>>>(hbufA, deg, ell, b1, W2, hbufB);
    // Layer 2->3: -> @W3 *dinv -> hbufA
    k_gatherW<<<GW_BLOCKS, 256, 0, stream>>>(hbufB, deg, ell, b2, W3, hbufA);
    // Layer 3 final: fp32 out
    k_gatherF<<<N_NODES / 4, 256, 0, stream>>>(hbufA, deg, ell, b3, out);
}

// Round 12
// 234.253 us; speedup vs baseline: 1.1559x; 1.0172x over previous
//
#include <hip/hip_runtime.h>
#include <math.h>

#define N_NODES 100000
#define N_EDGES 1200000
#define DIM 64
#define ELL_STRIDE 48        // ints per node row; deg<=48 safe (Poisson(12))
#define BNODES 128           // nodes per bucket (dst>>7)
#define NBUCKET ((N_NODES + BNODES - 1) / BNODES)   // 782 buckets
#define BIN_SHIFT 10         // coarse bin = dst>>10 (1024 nodes)
#define NBIN ((N_NODES + 1023) >> 10)               // 98 bins
#define BIN_CAP 16384        // edges per bin region (8 shards x 2048)
#define NSHARD 8             // tail shards per bin (chain depth 512 -> 64)
#define SHARD_CAP (BIN_CAP / NSHARD)                // 2048; mean 1531, +13 sigma
#define CAP 40               // staged edges per bin per fill block; mean 23.9, +3.3 sigma
#define BIN_BLOCKS 512
#define EPB ((N_EDGES + BIN_BLOCKS - 1) / BIN_BLOCKS)  // 2344 edges/block
#define GEMM1_BLOCKS (N_NODES / 16)            // 6250 (16 nodes/block, exact)
#define GW_BLOCKS (N_NODES / 16)               // 6250 (16 nodes/block, exact)

// packed edge: bits 0-16 = src (<131072), bits 17-26 = dst & 1023
#define PACK(s, dloc) (((unsigned)(dloc) << 17) | (unsigned)(s))
#define UNPACK_S(p)   ((int)((p) & 0x1FFFF))
#define UNPACK_D(p)   ((int)((p) >> 17))

typedef __attribute__((ext_vector_type(8))) short bf16x8;
typedef __attribute__((ext_vector_type(4))) float f32x4;

// bf16 pack/unpack (RTNE)
__device__ __forceinline__ unsigned short f2bf(float f) {
    union { float f; unsigned int u; } v; v.f = f;
    unsigned int r = v.u + 0x7FFF + ((v.u >> 16) & 1);
    return (unsigned short)(r >> 16);
}
__device__ __forceinline__ float bf2f(unsigned short us) {
    return __uint_as_float((unsigned int)us << 16);
}

// gather load: ell stores BYTE offsets (src*128); addr = h + (off + 2*lane)
#define LDH(boff) bf2f(*(const unsigned short*)((const char*)h + ((unsigned)(boff) + bo)))

// split 8 fp32 (two float4) into bf16 hi + residual lo fragments
__device__ __forceinline__ void split8(const float4 p, const float4 q,
                                       bf16x8& hi, bf16x8& lo) {
    float v[8] = {p.x, p.y, p.z, p.w, q.x, q.y, q.z, q.w};
#pragma unroll
    for (int j = 0; j < 8; ++j) {               // compile-time index (rule #20 safe)
        unsigned short h0 = f2bf(v[j]);
        hi[j] = (short)h0;
        lo[j] = (short)f2bf(v[j] - bf2f(h0));
    }
}

// ---------------- gemm1 tile via MFMA: 16 nodes/block, no LDS ---------------
// Fragment conventions HW-validated rounds 7-11 (absmax unchanged).
// NEEDS ~50-60 VGPRs: do NOT put occupancy launch_bounds on its kernel
// (round 9: (256,8) -> 32-VGPR cap -> spills -> +160 MB HBM).

__device__ __forceinline__ void gemm_block_mfma(int bid, const float* __restrict__ x,
                                                const float* __restrict__ W,
                                                unsigned short* __restrict__ h) {
    const int lane = (int)(threadIdx.x & 63);
    const int wv = (int)(threadIdx.x >> 6);
    const int base = bid * 16;
    const int g = lane >> 4;
    const int r16 = lane & 15;

    const float* xr = x + (size_t)(base + r16) * DIM + g * 8;
    float4 a0 = *(const float4*)(xr);
    float4 a1 = *(const float4*)(xr + 4);
    float4 a2 = *(const float4*)(xr + 32);
    float4 a3 = *(const float4*)(xr + 36);

    bf16x8 ah0, al0, ah1, al1;
    split8(a0, a1, ah0, al0);
    split8(a2, a3, ah1, al1);

    const int bcol = wv * 16 + r16;
    bf16x8 bh0, bl0, bh1, bl1;
#pragma unroll
    for (int j = 0; j < 8; ++j) {
        float w0 = W[(g * 8 + j) * DIM + bcol];
        float w1 = W[(g * 8 + j + 32) * DIM + bcol];
        unsigned short h0 = f2bf(w0);
        unsigned short h1 = f2bf(w1);
        bh0[j] = (short)h0; bl0[j] = (short)f2bf(w0 - bf2f(h0));
        bh1[j] = (short)h1; bl1[j] = (short)f2bf(w1 - bf2f(h1));
    }

    f32x4 acc = {0.f, 0.f, 0.f, 0.f};
    acc = __builtin_amdgcn_mfma_f32_16x16x32_bf16(ah0, bh0, acc, 0, 0, 0);
    acc = __builtin_amdgcn_mfma_f32_16x16x32_bf16(ah1, bh1, acc, 0, 0, 0);
    acc = __builtin_amdgcn_mfma_f32_16x16x32_bf16(al0, bh0, acc, 0, 0, 0);
    acc = __builtin_amdgcn_mfma_f32_16x16x32_bf16(al1, bh1, acc, 0, 0, 0);
    acc = __builtin_amdgcn_mfma_f32_16x16x32_bf16(ah0, bl0, acc, 0, 0, 0);
    acc = __builtin_amdgcn_mfma_f32_16x16x32_bf16(ah1, bl1, acc, 0, 0, 0);

#pragma unroll
    for (int r = 0; r < 4; ++r)
        h[(size_t)(base + g * 4 + r) * DIM + bcol] = f2bf(acc[r]);   // unscaled
}

// ---------------- fused: binning (blocks 0..511) || gemm1 (blocks 512..) ----
// Bin blocks FIRST (long pole starts at t=0; gemm blocks backfill).
// Bin tails sharded 8x (round 11: -4 us).

__global__ void __launch_bounds__(256) k_pre(const int* __restrict__ ei,
                                             const float* __restrict__ x,
                                             const float* __restrict__ W1,
                                             int* __restrict__ tail,
                                             unsigned* __restrict__ part,
                                             unsigned short* __restrict__ h) {
    __shared__ unsigned stg[NBIN * CAP];          // 15.7 KB u32 staging
    __shared__ int lcnt[NBIN];
    __shared__ int gbase[NBIN];
    __shared__ int gcnt[NBIN];

    if (blockIdx.x >= BIN_BLOCKS) {
        gemm_block_mfma(blockIdx.x - BIN_BLOCKS, x, W1, h);
        return;
    }
    const int tid = threadIdx.x;
    const int shard = blockIdx.x & (NSHARD - 1);
    for (int i = tid; i < NBIN; i += 256) lcnt[i] = 0;
    __syncthreads();

    const int e0 = blockIdx.x * EPB;
    const int eend = (e0 + EPB < N_EDGES) ? e0 + EPB : N_EDGES;
    for (int e = e0 + tid; e < eend; e += 256) {
        int s = ei[e], d = ei[N_EDGES + e];
        int bin = d >> BIN_SHIFT;
        unsigned pk = PACK(s, d & 1023);
        int pos = atomicAdd(&lcnt[bin], 1);
        if (pos < CAP) {
            stg[bin * CAP + pos] = pk;
        } else {                              // ~3.3-sigma tail, few hundred edges
            int gp = atomicAdd(&tail[(bin * NSHARD + shard) * 16], 1);
            part[(size_t)bin * BIN_CAP + shard * SHARD_CAP + gp] = pk;
        }
    }
    __syncthreads();
    if (tid < NBIN) {
        int c = lcnt[tid]; if (c > CAP) c = CAP;
        gcnt[tid] = c;
        gbase[tid] = c ? atomicAdd(&tail[(tid * NSHARD + shard) * 16], c) : 0;
    }
    __syncthreads();
    const int wv = tid >> 6, ln = tid & 63;   // wave-parallel flush (4 bins concurrent)
    for (int b = wv; b < NBIN; b += 4) {
        int c = gcnt[b];
        size_t gbb = (size_t)b * BIN_CAP + shard * SHARD_CAP + gbase[b];
        for (int i = ln; i < c; i += 64)
            part[gbb + i] = stg[b * CAP + i];
    }
}

// ---------------- bucket build: ELL slab in LDS + fused h1 scale ------------
// ELL entries are BYTE offsets into h (src * DIM * 2 = src << 7).
// Drains the 8 shard sub-segments of its parent bin.

__global__ void __launch_bounds__(256) k_bucket(const unsigned* __restrict__ part,
                                                const int* __restrict__ tail,
                                                int* __restrict__ ell,
                                                int* __restrict__ deg,
                                                unsigned short* __restrict__ hA,
                                                unsigned short* __restrict__ hB) {
    __shared__ int lcur[BNODES];
    __shared__ int lell[BNODES * ELL_STRIDE];   // 24 KB
    const int bucket = blockIdx.x;
    const int tid = threadIdx.x;

    for (int i = tid; i < BNODES; i += 256) lcur[i] = 0;
    __syncthreads();

    const int bin = bucket >> 3;                // dst>>10 == (dst>>7)>>3
    const int sub = bucket & 7;
    const int node0 = bucket * BNODES;
    const unsigned* pb = part + (size_t)bin * BIN_CAP;
#pragma unroll 1
    for (int s = 0; s < NSHARD; ++s) {          // independent appends; no barrier
        int n = tail[(bin * NSHARD + s) * 16];
        const unsigned* ps = pb + s * SHARD_CAP;
        for (int i = tid; i < n; i += 256) {
            unsigned p = ps[i];
            unsigned ld = (unsigned)(UNPACK_D(p) - (sub << 7));
            if (ld < BNODES) {
                int pos = atomicAdd(&lcur[ld], 1);
                if (pos < ELL_STRIDE) lell[ld * ELL_STRIDE + pos] = UNPACK_S(p) << 7;
            }
        }
    }
    __syncthreads();

    for (int idx = tid; idx < BNODES * ELL_STRIDE; idx += 256) {
        int ln = idx / ELL_STRIDE, sl = idx - ln * ELL_STRIDE;
        int dg = lcur[ln];
        int pe = (dg + 7) & ~7;
        if (pe < 16) pe = 16;
        if (sl >= dg && sl < pe) lell[idx] = N_NODES << 7;   // dummy zero row
    }
    __syncthreads();

    int4* dst4 = (int4*)(ell + (size_t)bucket * BNODES * ELL_STRIDE);
    const int4* src4 = (const int4*)lell;
    for (int i = tid; i < BNODES * ELL_STRIDE / 4; i += 256) dst4[i] = src4[i];
    for (int i = tid; i < BNODES; i += 256) deg[node0 + i] = lcur[i];

    // fused scale: hA[row] *= dinv; zero both dummy rows
    for (int i = tid; i < BNODES * 8; i += 256) {       // 8 uint4 per row
        int ln = i >> 3;
        int node = node0 + ln;
        if (node < N_NODES) {
            float dd = rsqrtf((float)(lcur[ln] + 1));
            uint4* p = (uint4*)(hA + (size_t)node * DIM) + (i & 7);
            uint4 v = *p;
            float lo, hi;
            lo = __uint_as_float(v.x << 16) * dd; hi = __uint_as_float(v.x & 0xFFFF0000u) * dd;
            v.x = (unsigned)f2bf(lo) | ((unsigned)f2bf(hi) << 16);
            lo = __uint_as_float(v.y << 16) * dd; hi = __uint_as_float(v.y & 0xFFFF0000u) * dd;
            v.y = (unsigned)f2bf(lo) | ((unsigned)f2bf(hi) << 16);
            lo = __uint_as_float(v.z << 16) * dd; hi = __uint_as_float(v.z & 0xFFFF0000u) * dd;
            v.z = (unsigned)f2bf(lo) | ((unsigned)f2bf(hi) << 16);
            lo = __uint_as_float(v.w << 16) * dd; hi = __uint_as_float(v.w & 0xFFFF0000u) * dd;
            v.w = (unsigned)f2bf(lo) | ((unsigned)f2bf(hi) << 16);
            *p = v;
        }
    }
    if (bucket == 0) {
        if (tid < 8)  ((uint4*)(hA + (size_t)N_NODES * DIM))[tid] = make_uint4(0, 0, 0, 0);
        else if (tid < 16) ((uint4*)(hB + (size_t)N_NODES * DIM))[tid - 8] = make_uint4(0, 0, 0, 0);
    }
}

// ---------------- fused gather+GEMM: agg -> +b -> relu -> @W(MFMA) -> *dinv -
// Round-7 body. THIS ROUND: m-loop fully unrolled + (256,4) (VGPR cap 85->128)
// to discriminate wave-issue-depth vs CU-MSHR as the gather limiter. r9 showed
// occupancy >50% is neutral, so the (256,6)->(256,4) release costs nothing.

__global__ void __launch_bounds__(256, 4)
k_gatherW(const unsigned short* __restrict__ h,
          const int* __restrict__ deg,
          const int* __restrict__ ell,
          const float* __restrict__ bvec,
          const float* __restrict__ W,
          unsigned short* __restrict__ hout) {
    __shared__ unsigned short shb[2048];        // [0..1023] A-hi, [1024..2047] A-lo
    const int tid = threadIdx.x;
    const int lane = tid & 63;
    const int wv = tid >> 6;
    const int base = blockIdx.x * 16;           // 6250*16 = 100000 exact
    const float bl = bvec[lane];
    const unsigned bo = 2u * (unsigned)lane;

#pragma unroll
    for (int m = 0; m < 4; ++m) {
        int node = base + wv * 4 + m;
        int dg = __builtin_amdgcn_readfirstlane(deg[node]);
        const int* row = ell + (size_t)node * ELL_STRIDE;

        int4 e0 = ((const int4*)row)[0];
        int4 e1 = ((const int4*)row)[1];
        int4 e2 = ((const int4*)row)[2];
        int4 e3 = ((const int4*)row)[3];
        float own = LDH((unsigned)node * 128u);

        float v0  = LDH(e0.x);
        float v1  = LDH(e0.y);
        float v2  = LDH(e0.z);
        float v3  = LDH(e0.w);
        float v4  = LDH(e1.x);
        float v5  = LDH(e1.y);
        float v6  = LDH(e1.z);
        float v7  = LDH(e1.w);
        float v8  = LDH(e2.x);
        float v9  = LDH(e2.y);
        float v10 = LDH(e2.z);
        float v11 = LDH(e2.w);
        float v12 = LDH(e3.x);
        float v13 = LDH(e3.y);
        float v14 = LDH(e3.z);
        float v15 = LDH(e3.w);

        float acc = ((own + v0) + (v1 + v2)) + ((v3 + v4) + (v5 + v6))
                  + ((v7 + v8) + (v9 + v10)) + ((v11 + v12) + ((v13 + v14) + v15));

        if (dg > 16) {                          // rare, wave-uniform
            int pe = (dg + 7) & ~7;
            for (int k = 16; k < pe; k += 8) {
                int4 a = *(const int4*)(row + k);
                int4 c = *(const int4*)(row + k + 4);
                float w0 = LDH(a.x);
                float w1 = LDH(a.y);
                float w2 = LDH(a.z);
                float w3 = LDH(a.w);
                float w4 = LDH(c.x);
                float w5 = LDH(c.y);
                float w6 = LDH(c.z);
                float w7 = LDH(c.w);
                acc += ((w0 + w1) + (w2 + w3)) + ((w4 + w5) + (w6 + w7));
            }
        }

        float dd = rsqrtf((float)(dg + 1));
        float o = fmaxf(fmaf(acc, dd, bl), 0.f);    // bias + relu (layers 1,2)
        // split-bf16 store, chunk-swizzled: chunk = lane>>3, phys = chunk^(row&7)
        unsigned short oh = f2bf(o);
        unsigned short ol = f2bf(o - bf2f(oh));
        int r16 = wv * 4 + m;
        int pc = r16 * 64 + (((lane >> 3) ^ (r16 & 7)) << 3) + (lane & 7);
        shb[pc] = oh;
        shb[1024 + pc] = ol;
    }
    __syncthreads();

    // B fragments: wave wv covers output cols [wv*16, wv*16+16)
    const int bcol = wv * 16 + (lane & 15);
    const int g = lane >> 4;
    bf16x8 bh0, bl0, bh1, bl1;
#pragma unroll
    for (int j = 0; j < 8; ++j) {
        float w0 = W[(g * 8 + j) * DIM + bcol];
        float w1 = W[(g * 8 + j + 32) * DIM + bcol];
        unsigned short h0 = f2bf(w0);
        unsigned short h1 = f2bf(w1);
        bh0[j] = (short)h0; bl0[j] = (short)f2bf(w0 - bf2f(h0));
        bh1[j] = (short)h1; bl1[j] = (short)f2bf(w1 - bf2f(h1));
    }

    // A fragments: row = lane&15; undo chunk swizzle
    const int arow = lane & 15;
    const int cs = arow & 7;
    bf16x8 ah0 = *(const bf16x8*)&shb[arow * 64 + ((g ^ cs) << 3)];
    bf16x8 ah1 = *(const bf16x8*)&shb[arow * 64 + (((g + 4) ^ cs) << 3)];
    bf16x8 al0 = *(const bf16x8*)&shb[1024 + arow * 64 + ((g ^ cs) << 3)];
    bf16x8 al1 = *(const bf16x8*)&shb[1024 + arow * 64 + (((g + 4) ^ cs) << 3)];

    f32x4 acc = {0.f, 0.f, 0.f, 0.f};
    acc = __builtin_amdgcn_mfma_f32_16x16x32_bf16(ah0, bh0, acc, 0, 0, 0);
    acc = __builtin_amdgcn_mfma_f32_16x16x32_bf16(ah1, bh1, acc, 0, 0, 0);
    acc = __builtin_amdgcn_mfma_f32_16x16x32_bf16(al0, bh0, acc, 0, 0, 0);
    acc = __builtin_amdgcn_mfma_f32_16x16x32_bf16(al1, bh1, acc, 0, 0, 0);
    acc = __builtin_amdgcn_mfma_f32_16x16x32_bf16(ah0, bl0, acc, 0, 0, 0);
    acc = __builtin_amdgcn_mfma_f32_16x16x32_bf16(ah1, bl1, acc, 0, 0, 0);

#pragma unroll
    for (int r = 0; r < 4; ++r) {
        int rr = g * 4 + r;                     // C/D: row=(lane>>4)*4+r
        float res = acc[r] * rsqrtf((float)(deg[base + rr] + 1));
        hout[(size_t)(base + rr) * DIM + wv * 16 + (lane & 15)] = f2bf(res);
    }
}

// ---------------- final gather: out = dinv*(sum) + b (fp32) -----------------
// 1 node/wave, 25000 blocks; (256,8), no spills — CONTROL, unchanged.

__global__ void __launch_bounds__(256, 8)
k_gatherF(const unsigned short* __restrict__ h,
          const int* __restrict__ deg,
          const int* __restrict__ ell, const float* __restrict__ b,
          float* __restrict__ out) {
    int node = blockIdx.x * 4 + (threadIdx.x >> 6);     // 25000*4 = 100000 exact
    const int lane = threadIdx.x & 63;
    const unsigned bo = 2u * (unsigned)lane;
    int dg = __builtin_amdgcn_readfirstlane(deg[node]);
    const int* row = ell + (size_t)node * ELL_STRIDE;

    int4 e0 = ((const int4*)row)[0];
    int4 e1 = ((const int4*)row)[1];
    int4 e2 = ((const int4*)row)[2];
    int4 e3 = ((const int4*)row)[3];
    float own = LDH((unsigned)node * 128u);

    float v0  = LDH(e0.x);
    float v1  = LDH(e0.y);
    float v2  = LDH(e0.z);
    float v3  = LDH(e0.w);
    float v4  = LDH(e1.x);
    float v5  = LDH(e1.y);
    float v6  = LDH(e1.z);
    float v7  = LDH(e1.w);
    float v8  = LDH(e2.x);
    float v9  = LDH(e2.y);
    float v10 = LDH(e2.z);
    float v11 = LDH(e2.w);
    float v12 = LDH(e3.x);
    float v13 = LDH(e3.y);
    float v14 = LDH(e3.z);
    float v15 = LDH(e3.w);

    float acc = ((own + v0) + (v1 + v2)) + ((v3 + v4) + (v5 + v6))
              + ((v7 + v8) + (v9 + v10)) + ((v11 + v12) + ((v13 + v14) + v15));

    if (dg > 16) {
        int pe = (dg + 7) & ~7;
        for (int k = 16; k < pe; k += 8) {
            int4 a = *(const int4*)(row + k);
            int4 c = *(const int4*)(row + k + 4);
            float w0 = LDH(a.x);
            float w1 = LDH(a.y);
            float w2 = LDH(a.z);
            float w3 = LDH(a.w);
            float w4 = LDH(c.x);
            float w5 = LDH(c.y);
            float w6 = LDH(c.z);
            float w7 = LDH(c.w);
            acc += ((w0 + w1) + (w2 + w3)) + ((w4 + w5) + (w6 + w7));
        }
    }

    float dd = rsqrtf((float)(dg + 1));
    out[(size_t)node * DIM + lane] = fmaf(acc, dd, b[lane]);
}

// ---------------- launch ----------------

extern "C" void kernel_launch(void* const* d_in, const int* in_sizes, int n_in,
                              void* d_out, int out_size, void* d_ws, size_t ws_size,
                              hipStream_t stream) {
    const float* x   = (const float*)d_in[0];
    const int*   ei  = (const int*)d_in[1];     // [2, E] row-major
    const float* W1  = (const float*)d_in[2];
    const float* b1  = (const float*)d_in[3];
    const float* W2  = (const float*)d_in[4];
    const float* b2  = (const float*)d_in[5];
    const float* W3  = (const float*)d_in[6];
    const float* b3  = (const float*)d_in[7];
    float* out = (float*)d_out;

    // ws layout; part (u32, 6.4 MB) overlays hbufB (disjoint lifetimes)
    char* ws = (char*)d_ws;
    int*            deg   = (int*)ws;                           // 400 KB
    int*            tailp = (int*)(ws + 0x70000);               // 98*8 x 64B = 50 KB
    int*            ell   = (int*)(ws + 0xD00000);              // 19.2 MB
    unsigned short* hbufA = (unsigned short*)(ws + 0x2000000);  // 12.8 MB (+dummy)
    unsigned short* hbufB = (unsigned short*)(ws + 0x2D00000);  // 12.85 MB
    unsigned*       part  = (unsigned*)(ws + 0x2D00000);        // overlay (NBIN*BIN_CAP*4)

    // zero the 98*8 sharded bin tails (stream-ordered)
    hipMemsetAsync(tailp, 0, NBIN * NSHARD * 16 * sizeof(int), stream);

    // binning (blocks 0..511, long pole, starts first) || gemm1 MFMA
    k_pre<<<BIN_BLOCKS + GEMM1_BLOCKS, 256, 0, stream>>>(ei, x, W1, tailp, part, hbufA);
    // bucket ELL build (byte-offset entries, 8 shard segments) + deg + scale
    k_bucket<<<NBUCKET, 256, 0, stream>>>(part, tailp, ell, deg, hbufA, hbufB);

    // Layer 1->2: gather(h1') + b1 + relu -> @W2 *dinv -> hbufB
    k_gatherW<<<GW_BLOCKS, 256, 0, stream>>>(hbufA, deg, ell, b1, W2, hbufB);
    // Layer 2->3: -> @W3 *dinv -> hbufA
    k_gatherW<<<GW_BLOCKS, 256, 0, stream>>>(hbufB, deg, ell, b2, W3, hbufA);
    // Layer 3 final: fp32 out
    k_gatherF<<<N_NODES / 4, 256, 0, stream>>>(hbufA, deg, ell, b3, out);
}